// Round 4
// baseline (209.133 us; speedup 1.0000x reference)
//
#include <hip/hip_runtime.h>
#include <stdint.h>

#define INS 768
#define OUTS 64
#define BB 8
#define SS 2048

typedef __attribute__((ext_vector_type(8))) short short8;
typedef __attribute__((ext_vector_type(4))) float f32x4;

__device__ inline unsigned short f2bf(float f) {
  union { float f; uint32_t u; } v; v.f = f;
  uint32_t r = v.u + 0x7FFFu + ((v.u >> 16) & 1u);  // RNE
  return (unsigned short)(r >> 16);
}

__device__ inline short8 cvt8(float4 a, float4 b) {
  short8 r;
  r[0] = (short)f2bf(a.x); r[1] = (short)f2bf(a.y);
  r[2] = (short)f2bf(a.z); r[3] = (short)f2bf(a.w);
  r[4] = (short)f2bf(b.x); r[5] = (short)f2bf(b.y);
  r[6] = (short)f2bf(b.z); r[7] = (short)f2bf(b.w);
  return r;
}

// ---------------- kernel 1: tiled transpose-cast of weights ------------------
__global__ __launch_bounds__(256) void cast_weights(
    const float* __restrict__ Wq, const float* __restrict__ bq,
    const float* __restrict__ Wk, const float* __restrict__ bk,
    const float* __restrict__ Wv, const float* __restrict__ bv,
    unsigned short* __restrict__ Wt, float* __restrict__ bc) {
  __shared__ float Ls[64][65];
  const int mat = blockIdx.x / 12, kt = blockIdx.x % 12;
  const float* W; const float* bs; float scale;
  if (mat == 0)      { W = Wq; bs = bq; scale = 0.125f; }
  else if (mat == 1) { W = Wk; bs = bk; scale = 1.0f; }
  else               { W = Wv; bs = bv; scale = 1.0f; }
  const int tid = threadIdx.x;
#pragma unroll
  for (int rep = 0; rep < 4; ++rep) {
    int idx = tid + rep * 256, r = idx >> 4, c4 = idx & 15;
    float4 v = *reinterpret_cast<const float4*>(W + (size_t)(kt * 64 + r) * 64 + c4 * 4);
    Ls[r][c4 * 4 + 0] = v.x; Ls[r][c4 * 4 + 1] = v.y;
    Ls[r][c4 * 4 + 2] = v.z; Ls[r][c4 * 4 + 3] = v.w;
  }
  __syncthreads();
  const int n = tid >> 2, ch = tid & 3;
  __align__(16) unsigned short tmp[16];
#pragma unroll
  for (int j = 0; j < 16; ++j) tmp[j] = f2bf(Ls[ch * 16 + j][n] * scale);
  unsigned short* dst = Wt + (size_t)(mat * 64 + n) * INS + kt * 64 + ch * 16;
  *reinterpret_cast<int4*>(dst)     = *reinterpret_cast<const int4*>(tmp);
  *reinterpret_cast<int4*>(dst + 8) = *reinterpret_cast<const int4*>(tmp + 8);
  if (kt == 0 && tid < 64) bc[mat * 64 + tid] = bs[tid] * scale;
}

// ---------------- kernel 2: barrier-free QKV GEMM, ping-pong pipelined -------
// wave = 16 rows x 48 channels; block = 16 rows x 192 ch (4 waves share X via
// L1). grid 1024 -> 16 waves/CU. Two named register sets, loads issued before
// the dependent MFMA block of the OTHER set -> vmcnt never drains to 0.
struct QkvF { float4 x0, x1; short8 b[3]; };

__global__ __launch_bounds__(256) void qkv_gemm(
    const float* __restrict__ X, const unsigned short* __restrict__ Wt,
    const float* __restrict__ bc,
    unsigned short* __restrict__ Qg, unsigned short* __restrict__ Kg,
    unsigned short* __restrict__ Vtg) {
  const int tid  = threadIdx.x;
  const int wave = tid >> 6, lane = tid & 63;
  const int quad = lane >> 4, l16 = lane & 15;
  const int row0 = blockIdx.x * 16;
  const float* Xr = X + (size_t)(row0 + l16) * INS + quad * 8;
  const unsigned short* Wb = Wt + (size_t)(wave * 48 + l16) * INS + quad * 8;

  f32x4 acc[3];
#pragma unroll
  for (int i = 0; i < 3; ++i) acc[i] = (f32x4){0.f, 0.f, 0.f, 0.f};

  auto load = [&](int kc, QkvF& f) {
    const int ko = kc * 32;
    f.x0 = *reinterpret_cast<const float4*>(Xr + ko);
    f.x1 = *reinterpret_cast<const float4*>(Xr + ko + 4);
#pragma unroll
    for (int nt = 0; nt < 3; ++nt)
      f.b[nt] = *reinterpret_cast<const short8*>(Wb + (size_t)nt * 16 * INS + ko);
  };
  auto comp = [&](QkvF& f) {
    short8 a = cvt8(f.x0, f.x1);
#pragma unroll
    for (int nt = 0; nt < 3; ++nt)
      acc[nt] = __builtin_amdgcn_mfma_f32_16x16x32_bf16(a, f.b[nt], acc[nt], 0, 0, 0);
  };

  QkvF fa, fb;
  load(0, fa);
  for (int kc = 0; kc < 24; kc += 2) {
    load(kc + 1, fb);
    comp(fa);
    if (kc + 2 < 24) load(kc + 2, fa);
    comp(fb);
  }

  // epilogue: Q,K row-major bf16; V transposed Vt[batch][d][s]
  const int gm0 = row0 + quad * 4;
#pragma unroll
  for (int nt = 0; nt < 3; ++nt) {
    const int n = wave * 48 + nt * 16 + l16;
    const float bias = bc[n];
    if (n < 128) {
      unsigned short* dstbase = (n < 64) ? Qg : Kg;
      const int nn = n & 63;
#pragma unroll
      for (int r = 0; r < 4; ++r)
        dstbase[(size_t)(gm0 + r) * OUTS + nn] = f2bf(acc[nt][r] + bias);
    } else {
      const int d = n - 128;
      const int batch = gm0 >> 11, s0 = gm0 & 2047;
      ushort4 pk;
      pk.x = f2bf(acc[nt][0] + bias);
      pk.y = f2bf(acc[nt][1] + bias);
      pk.z = f2bf(acc[nt][2] + bias);
      pk.w = f2bf(acc[nt][3] + bias);
      *reinterpret_cast<ushort4*>(&Vtg[((size_t)batch * OUTS + d) * SS + s0]) = pk;
    }
  }
}

// ---------------- kernel 3: barrier-free attention, ping-pong pipelined ------
// wave = 16 q-rows x 512 keys (key-split 4). grid 1024 -> 16 waves/CU.
#define LDP 40
struct AttF { short8 k[2][2]; short8 v[4]; };

__global__ __launch_bounds__(256) void attn(
    const unsigned short* __restrict__ Qg, const unsigned short* __restrict__ Kg,
    const unsigned short* __restrict__ Vtg,
    float* __restrict__ OP, float* __restrict__ LS) {
  __shared__ __align__(16) unsigned short Ps[4][16 * LDP];
  const int tid  = threadIdx.x;
  const int wave = tid >> 6, lane = tid & 63;
  const int quad = lane >> 4, l16 = lane & 15;
  const int ksl = blockIdx.x & 3;
  const int qt  = (blockIdx.x >> 2) & 31;
  const int bt  = blockIdx.x >> 7;
  const int q0 = qt * 64 + wave * 16;
  const unsigned short* Qb = Qg + (size_t)bt * SS * OUTS;
  const unsigned short* Kb = Kg + (size_t)bt * SS * OUTS;
  const unsigned short* Vb = Vtg + (size_t)bt * OUTS * SS;
  const int jbeg = ksl * 512;

  short8 aq[2];
#pragma unroll
  for (int ks = 0; ks < 2; ++ks)
    aq[ks] = *reinterpret_cast<const short8*>(
        Qb + (size_t)(q0 + l16) * OUTS + ks * 32 + quad * 8);

  f32x4 oacc[4];
#pragma unroll
  for (int nt = 0; nt < 4; ++nt) oacc[nt] = (f32x4){0.f, 0.f, 0.f, 0.f};
  float lsum[4] = {0.f, 0.f, 0.f, 0.f};
  unsigned short* Pw = Ps[wave];

  auto load = [&](int it, AttF& f) {
    const int j0 = jbeg + it * 32;
#pragma unroll
    for (int nt2 = 0; nt2 < 2; ++nt2)
#pragma unroll
      for (int ks = 0; ks < 2; ++ks)
        f.k[nt2][ks] = *reinterpret_cast<const short8*>(
            Kb + (size_t)(j0 + nt2 * 16 + l16) * OUTS + ks * 32 + quad * 8);
#pragma unroll
    for (int nt = 0; nt < 4; ++nt)
      f.v[nt] = *reinterpret_cast<const short8*>(
          Vb + (size_t)(nt * 16 + l16) * SS + j0 + quad * 8);
  };
  auto comp = [&](AttF& f) {
    f32x4 sc[2];
    sc[0] = (f32x4){0.f,0.f,0.f,0.f}; sc[1] = (f32x4){0.f,0.f,0.f,0.f};
#pragma unroll
    for (int ks = 0; ks < 2; ++ks)
#pragma unroll
      for (int nt2 = 0; nt2 < 2; ++nt2)
        sc[nt2] = __builtin_amdgcn_mfma_f32_16x16x32_bf16(aq[ks], f.k[nt2][ks], sc[nt2], 0, 0, 0);
#pragma unroll
    for (int nt2 = 0; nt2 < 2; ++nt2)
#pragma unroll
      for (int r = 0; r < 4; ++r) {
        float p = __expf(sc[nt2][r]);
        lsum[r] += p;
        Pw[(quad * 4 + r) * LDP + nt2 * 16 + l16] = f2bf(p);
      }
    short8 ap = *reinterpret_cast<const short8*>(&Pw[l16 * LDP + quad * 8]);
#pragma unroll
    for (int nt = 0; nt < 4; ++nt)
      oacc[nt] = __builtin_amdgcn_mfma_f32_16x16x32_bf16(ap, f.v[nt], oacc[nt], 0, 0, 0);
  };

  AttF fa, fb;
  load(0, fa);
  for (int it = 0; it < 16; it += 2) {
    load(it + 1, fb);
    comp(fa);
    if (it + 2 < 16) load(it + 2, fa);
    comp(fb);
  }

  // reduce lsum across the 16 l16-lanes (strides 1,2,4,8 keep the quad group)
#pragma unroll
  for (int st = 1; st < 16; st <<= 1)
#pragma unroll
    for (int r = 0; r < 4; ++r) lsum[r] += __shfl_xor(lsum[r], st, 64);

  float* OPb = OP + ((size_t)ksl * BB + bt) * SS * OUTS;
#pragma unroll
  for (int nt = 0; nt < 4; ++nt)
#pragma unroll
    for (int r = 0; r < 4; ++r) {
      int q = q0 + quad * 4 + r;
      OPb[(size_t)q * OUTS + nt * 16 + l16] = oacc[nt][r];
    }
  if (l16 == 0) {
#pragma unroll
    for (int r = 0; r < 4; ++r)
      LS[(size_t)ksl * BB * SS + bt * SS + q0 + quad * 4 + r] = lsum[r];
  }
}

// ---------------- kernel 4: combine key-split partials -----------------------
__global__ __launch_bounds__(256) void combine(
    const float* __restrict__ OP, const float* __restrict__ LS,
    float* __restrict__ out) {
  const size_t i4 = (size_t)blockIdx.x * 256 + threadIdx.x;  // float4 index
  const size_t row = (i4 * 4) >> 6;                          // bt*S + q
  float4 o = make_float4(0.f, 0.f, 0.f, 0.f);
  float l = 0.f;
#pragma unroll
  for (int ks = 0; ks < 4; ++ks) {
    float4 t = reinterpret_cast<const float4*>(OP + (size_t)ks * BB * SS * OUTS)[i4];
    o.x += t.x; o.y += t.y; o.z += t.z; o.w += t.w;
    l += LS[(size_t)ks * BB * SS + row];
  }
  const float inv = 1.0f / l;
  reinterpret_cast<float4*>(out)[i4] = make_float4(o.x * inv, o.y * inv, o.z * inv, o.w * inv);
}

extern "C" void kernel_launch(void* const* d_in, const int* in_sizes, int n_in,
                              void* d_out, int out_size, void* d_ws, size_t ws_size,
                              hipStream_t stream) {
  const float* X  = (const float*)d_in[0];
  const float* Wq = (const float*)d_in[1];
  const float* bq = (const float*)d_in[2];
  const float* Wk = (const float*)d_in[3];
  const float* bk = (const float*)d_in[4];
  const float* Wv = (const float*)d_in[5];
  const float* bv = (const float*)d_in[6];
  float* out = (float*)d_out;

  char* ws = (char*)d_ws;
  unsigned short* Qg  = (unsigned short*)(ws);                              // 2 MB
  unsigned short* Kg  = (unsigned short*)(ws + (size_t)2 * 1024 * 1024);    // 2 MB
  unsigned short* Vtg = (unsigned short*)(ws + (size_t)4 * 1024 * 1024);    // 2 MB
  unsigned short* Wt  = (unsigned short*)(ws + (size_t)6 * 1024 * 1024);    // 288 KB
  float*          bc  = (float*)(ws + (size_t)6 * 1024 * 1024 + 294912);    // 768 B
  float*          OP  = (float*)(ws + (size_t)7 * 1024 * 1024);             // 16 MB
  float*          LS  = (float*)(ws + (size_t)23 * 1024 * 1024);            // 256 KB

  cast_weights<<<36, 256, 0, stream>>>(Wq, bq, Wk, bk, Wv, bv, Wt, bc);
  qkv_gemm<<<1024, 256, 0, stream>>>(X, Wt, bc, Qg, Kg, Vtg);
  attn<<<1024, 256, 0, stream>>>(Qg, Kg, Vtg, OP, LS);
  combine<<<1024, 256, 0, stream>>>(OP, LS, out);
}